// Round 20
// baseline (928.511 us; speedup 1.0000x reference)
//
#include <hip/hip_runtime.h>
#include <math.h>

#define NNODES 100000
#define NEDGES 1200000
#define HD 64
#define NLAYERS 8
#define NGRAPH 100
#define PPART 32          // pooling partitions per graph
#define NPART 8           // histogram partials (≈ XCD count)
#define C8 16777216.0f    // 8^8 = 2^24, exact in f32

typedef _Float16 f16;
typedef __attribute__((ext_vector_type(2))) _Float16 f16x2;
typedef __attribute__((ext_vector_type(8))) _Float16 f16x8;
typedef __attribute__((ext_vector_type(4))) float f32x4;

// ---------- lin0: x0 = relu(pos @ lin0_w + lin0_b), fp16 (scale c_0 = 1) ----------
__global__ void lin0_k(const float* __restrict__ pos, const float* __restrict__ w,
                       const float* __restrict__ b, f16* __restrict__ x0h, int total) {
    int i = blockIdx.x * blockDim.x + threadIdx.x;
    if (i >= total) return;
    int n = i >> 6, h = i & 63;
    float p0 = pos[n * 3 + 0], p1 = pos[n * 3 + 1], p2 = pos[n * 3 + 2];
    float v = fmaf(p0, w[h], fmaf(p1, w[64 + h], fmaf(p2, w[128 + h], b[h])));
    x0h[i] = (f16)fmaxf(v, 0.0f);
}

// ---------- CSR build (XCD-local partial histograms, r16-proven) ----------
__global__ void hist_k(const int* __restrict__ dst, int* __restrict__ degp,
                       int* __restrict__ rank, int E) {
    int e = blockIdx.x * 256 + threadIdx.x;
    int p = blockIdx.x & (NPART - 1);
    if (e < E) rank[e] = atomicAdd(&degp[p * NNODES + dst[e]], 1);
}

__global__ void offs_k(const int* __restrict__ degp, int* __restrict__ poff,
                       int* __restrict__ deg, int n) {
    int d = blockIdx.x * blockDim.x + threadIdx.x;
    if (d >= n) return;
    int s = 0;
#pragma unroll
    for (int p = 0; p < NPART; ++p) {
        poff[p * n + d] = s;
        s += degp[p * n + d];
    }
    deg[d] = s;
}

__global__ void scan_part_k(const int* __restrict__ deg, int* __restrict__ bsum, int n) {
    __shared__ int s[256];
    int t = threadIdx.x;
    int i = blockIdx.x * 256 + t;
    s[t] = (i < n) ? deg[i] : 0;
    __syncthreads();
    for (int off = 128; off > 0; off >>= 1) {
        if (t < off) s[t] += s[t + off];
        __syncthreads();
    }
    if (t == 0) bsum[blockIdx.x] = s[0];
}

__global__ void scan_mid_k(const int* __restrict__ bsum, int* __restrict__ boff,
                           int nblk, int* __restrict__ roff, int n) {
    __shared__ int s[512];
    int t = threadIdx.x;
    int v = (t < nblk) ? bsum[t] : 0;
    s[t] = v;
    __syncthreads();
    for (int off = 1; off < 512; off <<= 1) {
        int u = (t >= off) ? s[t - off] : 0;
        __syncthreads();
        s[t] += u;
        __syncthreads();
    }
    if (t < nblk) boff[t] = s[t] - v;          // exclusive
    if (t == nblk - 1) roff[n] = s[t];         // == E
}

__global__ void scan_final_k(const int* __restrict__ deg, const int* __restrict__ boff,
                             int* __restrict__ roff, int n) {
    __shared__ int s[256];
    int t = threadIdx.x;
    int i = blockIdx.x * 256 + t;
    int v = (i < n) ? deg[i] : 0;
    s[t] = v;
    __syncthreads();
    for (int off = 1; off < 256; off <<= 1) {
        int u = (t >= off) ? s[t - off] : 0;
        __syncthreads();
        s[t] += u;
        __syncthreads();
    }
    if (i < n) roff[i] = boff[blockIdx.x] + s[t] - v;   // exclusive scan
}

__global__ void fill_k(const int* __restrict__ src, const int* __restrict__ dst,
                       const int* __restrict__ roff, const int* __restrict__ poff,
                       const int* __restrict__ rank, int* __restrict__ csr, int E) {
    int e = blockIdx.x * 256 + threadIdx.x;
    if (e < E) {
        int d = dst[e];
        int p = (e >> 8) & (NPART - 1);
        csr[roff[d] + poff[p * NNODES + d] + rank[e]] = src[e];
    }
}

// ---------- prep: pack 9 matrices into MFMA B-fragment order ----------
__global__ void prep_k(const float* __restrict__ cw, const float* __restrict__ l1w,
                       f16* __restrict__ Bpack) {
    int t = blockIdx.x * blockDim.x + threadIdx.x;
    if (t >= 9 * 4 * 2 * 64) return;
    int mat = t >> 9, rem = t & 511;
    int ct = rem >> 7, kk = (rem >> 6) & 1, lane = rem & 63;
    int g = lane >> 4, r = lane & 15;
    f16* outp = Bpack + (size_t)t * 8;
    if (mat < 8) {
        float beta = logf(0.5f / (float)(mat + 1) + 1.0f);
        const float* W = cw + (size_t)mat * 4096;
        for (int j = 0; j < 8; ++j) {
            int row = 32 * kk + 8 * g + j;
            int col = 16 * ct + r;
            float m = beta * W[row * 64 + col];
            if (row == col) m += 1.0f - beta;
            outp[j] = (f16)(0.125f * m);
        }
    } else {
        for (int j = 0; j < 8; ++j) {
            int row = 32 * kk + 8 * g + j;
            int col = 16 * ct + r;
            outp[j] = (f16)l1w[row * 64 + col];
        }
    }
}

// ---------- aggregate: channel-split gather, h -> hbuf ----------
// chalf = blockIdx&1: with round-robin block->XCD dispatch, even XCDs touch
// ONLY channel lines 0-31, odd XCDs only 32-63 -> per-XCD compulsory L2-miss
// footprint HALVES (the measured 67MB/layer ~= 8 XCDs x compulsory x-bytes
// at ~64B/cyc/XCD L2<->L3 was the invariant 50us floor of r14-r19).
// Gather: 4 edge-groups of 16 lanes, each lane f16x2 -> ONE instruction
// covers FOUR 64B lines; 2x shfl_xor reduces groups. h = 0.9*agg +
// x0scale*x0, rounded to f16 (identical rounding to the old Htile path).
__global__ __launch_bounds__(256, 8) void agg_k(
    const f16* __restrict__ xin, f16* __restrict__ hbuf,
    const f16* __restrict__ x0,
    const int* __restrict__ roff, const int* __restrict__ csr,
    float x0scale) {
    const int b     = blockIdx.x;
    const int chalf = b & 1;                  // == XCD parity (round-robin)
    const int tile  = b >> 1;
    const int tid   = threadIdx.x;
    const int lane  = tid & 63;
    const int wslot = tid >> 6;
    const int grp   = lane >> 4;              // edge group 0..3
    const int cl    = lane & 15;              // channel-pair within half
    const int cbase = (chalf << 5) + (cl << 1);
    const int nbase = (tile << 4) + (wslot << 2);
#pragma unroll 1
    for (int i = 0; i < 4; ++i) {
        const int n = nbase + i;
        const int beg = roff[n], end = roff[n + 1];
        float sl = 0.0f, sh = 0.0f;
#pragma unroll 1
        for (int e = beg; e < end; e += 4) {
            int ee = e + grp;
            int idx = csr[ee < end ? ee : end - 1];
            float m = (ee < end) ? 1.0f : 0.0f;
            f16x2 v = *(const f16x2*)(xin + (idx << 6) + cbase);
            sl = fmaf(m, (float)v.x, sl);
            sh = fmaf(m, (float)v.y, sh);
        }
        sl += __shfl_xor(sl, 16, 64);
        sh += __shfl_xor(sh, 16, 64);
        sl += __shfl_xor(sl, 32, 64);
        sh += __shfl_xor(sh, 32, 64);
        if (grp == 0) {
            f16x2 x0v = *(const f16x2*)(x0 + (n << 6) + cbase);
            f16x2 hw;
            hw.x = (f16)fmaf(0.9f, sl, x0scale * (float)x0v.x);
            hw.y = (f16)fmaf(0.9f, sh, x0scale * (float)x0v.y);
            *(f16x2*)(hbuf + (n << 6) + cbase) = hw;
        }
    }
}

// ---------- GEMM: y = x @ M (B-frags prepacked), optional relu ----------
__global__ __launch_bounds__(256, 8) void gemm_k(
    const f16* __restrict__ xin, f16* __restrict__ yout,
    const f16* __restrict__ Bp, int nblocks, int doRelu) {
    const int lane  = threadIdx.x & 63;
    const int wslot = threadIdx.x >> 6;
    const f16x8 b0 = *(const f16x8*)(Bp + (size_t)((wslot * 2 + 0) * 64 + lane) * 8);
    const f16x8 b1 = *(const f16x8*)(Bp + (size_t)((wslot * 2 + 1) * 64 + lane) * 8);
    const int ar = lane & 15, ag = lane >> 4;
    for (int tile = blockIdx.x; tile < NNODES / 16; tile += nblocks) {
        const int nbase = tile << 4;
        f16x8 a0 = *(const f16x8*)(xin + ((size_t)(nbase + ar) << 6) + (ag << 3));
        f16x8 a1 = *(const f16x8*)(xin + ((size_t)(nbase + ar) << 6) + (ag << 3) + 32);
        f32x4 acc = {0.0f, 0.0f, 0.0f, 0.0f};
        acc = __builtin_amdgcn_mfma_f32_16x16x32_f16(a0, b0, acc, 0, 0, 0);
        acc = __builtin_amdgcn_mfma_f32_16x16x32_f16(a1, b1, acc, 0, 0, 0);
        const int col = (wslot << 4) + ar;
        const int rbase = nbase + (ag << 2);
#pragma unroll
        for (int j = 0; j < 4; ++j) {
            float r = doRelu ? fmaxf(acc[j], 0.0f) : acc[j];
            yout[((rbase + j) << 6) + col] = (f16)r;
        }
    }
}

// ---------- segment max over lin1 output (pure fp16 row-max) ----------
__device__ __forceinline__ int lbound(const int* __restrict__ a, int n, int v) {
    int lo = 0, hi = n;
    while (lo < hi) { int mid = (lo + hi) >> 1; if (a[mid] < v) lo = mid + 1; else hi = mid; }
    return lo;
}

__global__ __launch_bounds__(256, 8) void segmax_k(
    const f16* __restrict__ y, const int* __restrict__ batch,
    float* __restrict__ pmax) {
    __shared__ float wm[4][64];
    const int tid   = threadIdx.x;
    const int lane  = tid & 63;
    const int wslot = tid >> 6;
    const int g = blockIdx.x / PPART, part = blockIdx.x % PPART;
    const int lo = lbound(batch, NNODES, g);
    const int hi = lbound(batch, NNODES, g + 1);
    const int cnt = hi - lo;
    const int qlo = lo + (cnt * part) / PPART;
    const int qhi = lo + (cnt * (part + 1)) / PPART;
    float vmax = -INFINITY;
    for (int n = qlo + wslot; n < qhi; n += 4)
        vmax = fmaxf(vmax, (float)y[(n << 6) + lane]);
    wm[wslot][lane] = vmax;
    __syncthreads();
    if (tid < 64) {
        float m = fmaxf(fmaxf(wm[0][tid], wm[1][tid]), fmaxf(wm[2][tid], wm[3][tid]));
        pmax[blockIdx.x * 64 + tid] = m;
    }
}

// combine partitions + undo 8^8 scale + add bias (max commutes with affine)
__global__ void poolcomb_k(const float* __restrict__ pmax,
                           const float* __restrict__ bvec,
                           float* __restrict__ pooled) {
    int i = blockIdx.x * blockDim.x + threadIdx.x;
    if (i >= NGRAPH * 64) return;
    int g = i >> 6, lane = i & 63;
    float m = -INFINITY;
    for (int p = 0; p < PPART; ++p)
        m = fmaxf(m, pmax[(PPART * g + p) * 64 + lane]);
    pooled[i] = fmaf(C8, m, bvec[lane]);   // -inf stays -inf; head guards
}

// ---------- head: MLP + BN + out + log_softmax, single block ----------
__global__ __launch_bounds__(256) void head_k(
    const float* __restrict__ pooled,
    const float* __restrict__ m1w, const float* __restrict__ m1b,
    const float* __restrict__ g1, const float* __restrict__ be1,
    const float* __restrict__ m2w, const float* __restrict__ m2b,
    const float* __restrict__ g2, const float* __restrict__ be2,
    const float* __restrict__ ow, const float* __restrict__ ob,
    float* __restrict__ out) {
    __shared__ float A[NGRAPH * 64];
    __shared__ float B[NGRAPH * 64];
    __shared__ float mu[64], rs[64];
    __shared__ float LG[NGRAPH * 10];
    int t = threadIdx.x;
    for (int i = t; i < NGRAPH * 64; i += 256) {
        float f = pooled[i];
        if (!isfinite(f)) f = 0.0f;   // empty-segment guard
        A[i] = f;
    }
    __syncthreads();
    // ---- mlp1 ----
    for (int i = t; i < NGRAPH * 64; i += 256) {
        int g = i >> 6, j = i & 63;
        float acc = m1b[j];
        for (int k = 0; k < 64; ++k) acc = fmaf(A[(g << 6) + k], m1w[k * 64 + j], acc);
        B[i] = acc;
    }
    __syncthreads();
    if (t < 64) {
        float sm = 0.0f, sq = 0.0f;
        for (int g = 0; g < NGRAPH; ++g) { float z = B[g * 64 + t]; sm += z; sq += z * z; }
        float m = sm * (1.0f / NGRAPH);
        float var = sq * (1.0f / NGRAPH) - m * m;
        mu[t] = m; rs[t] = rsqrtf(var + 1e-5f);
    }
    __syncthreads();
    for (int i = t; i < NGRAPH * 64; i += 256) {
        int j = i & 63;
        float z = fmaf((B[i] - mu[j]) * rs[j], g1[j], be1[j]);
        A[i] = fmaxf(z, 0.0f);
    }
    __syncthreads();
    // ---- mlp2 ----
    for (int i = t; i < NGRAPH * 64; i += 256) {
        int g = i >> 6, j = i & 63;
        float acc = m2b[j];
        for (int k = 0; k < 64; ++k) acc = fmaf(A[(g << 6) + k], m2w[k * 64 + j], acc);
        B[i] = acc;
    }
    __syncthreads();
    if (t < 64) {
        float sm = 0.0f, sq = 0.0f;
        for (int g = 0; g < NGRAPH; ++g) { float z = B[g * 64 + t]; sm += z; sq += z * z; }
        float m = sm * (1.0f / NGRAPH);
        float var = sq * (1.0f / NGRAPH) - m * m;
        mu[t] = m; rs[t] = rsqrtf(var + 1e-5f);
    }
    __syncthreads();
    for (int i = t; i < NGRAPH * 64; i += 256) {
        int j = i & 63;
        float z = fmaf((B[i] - mu[j]) * rs[j], g2[j], be2[j]);
        A[i] = fmaxf(z, 0.0f);
    }
    __syncthreads();
    // ---- out + log_softmax ----
    for (int i = t; i < NGRAPH * 10; i += 256) {
        int g = i / 10, j = i - g * 10;
        float acc = ob[j];
        for (int k = 0; k < 64; ++k) acc = fmaf(A[(g << 6) + k], ow[k * 10 + j], acc);
        LG[i] = acc;
    }
    __syncthreads();
    if (t < NGRAPH) {
        float m = -1e30f;
        for (int j = 0; j < 10; ++j) m = fmaxf(m, LG[t * 10 + j]);
        float s = 0.0f;
        for (int j = 0; j < 10; ++j) s += expf(LG[t * 10 + j] - m);
        float lse = m + logf(s);
        for (int j = 0; j < 10; ++j) out[t * 10 + j] = LG[t * 10 + j] - lse;
    }
}

extern "C" void kernel_launch(void* const* d_in, const int* in_sizes, int n_in,
                              void* d_out, int out_size, void* d_ws, size_t ws_size,
                              hipStream_t stream) {
    const float* pos   = (const float*)d_in[0];
    const int*   eidx  = (const int*)d_in[1];
    const int*   batch = (const int*)d_in[2];
    const float* l0w   = (const float*)d_in[3];
    const float* l0b   = (const float*)d_in[4];
    const float* cw    = (const float*)d_in[5];
    const float* l1w   = (const float*)d_in[6];
    const float* l1b   = (const float*)d_in[7];
    const float* m1w   = (const float*)d_in[8];
    const float* m1b   = (const float*)d_in[9];
    const float* g1    = (const float*)d_in[10];
    const float* b1    = (const float*)d_in[11];
    const float* m2w   = (const float*)d_in[12];
    const float* m2b   = (const float*)d_in[13];
    const float* g2    = (const float*)d_in[14];
    const float* b2    = (const float*)d_in[15];
    const float* ow    = (const float*)d_in[16];
    const float* ob    = (const float*)d_in[17];
    float* out = (float*)d_out;
    const int* src = eidx;
    const int* dst = eidx + NEDGES;

    size_t off = 0;
    auto alloc = [&](size_t bytes) -> void* {
        void* p = (char*)d_ws + off;
        off += (bytes + 255) & ~(size_t)255;
        return p;
    };
    f16*   x0h    = (f16*)alloc((size_t)NNODES * 64 * 2);
    f16*   xA     = (f16*)alloc((size_t)NNODES * 64 * 2);
    f16*   xB     = (f16*)alloc((size_t)NNODES * 64 * 2);
    f16*   hbuf   = (f16*)alloc((size_t)NNODES * 64 * 2);
    int*   deg    = (int*)alloc((size_t)NNODES * 4);
    int*   degp   = (int*)alloc((size_t)NPART * NNODES * 4);   // 3.2MB
    int*   poff   = (int*)alloc((size_t)NPART * NNODES * 4);   // 3.2MB
    int*   roff   = (int*)alloc((size_t)(NNODES + 1) * 4);
    const int NBLK = (NNODES + 255) / 256;                     // 391
    int*   bsum   = (int*)alloc((size_t)NBLK * 4);
    int*   boff   = (int*)alloc((size_t)NBLK * 4);
    int*   csr    = (int*)alloc((size_t)NEDGES * 4);
    float* pooled = (float*)alloc((size_t)NGRAPH * 64 * 4);
    float* pmax   = (float*)alloc((size_t)NGRAPH * PPART * 64 * 4);
    f16*   Bpack  = (f16*)alloc((size_t)9 * 4 * 2 * 64 * 8 * 2);   // 72KB
    int*   rank   = (int*)xB;   // xB dead until layer 1 writes it

    hipMemsetAsync(degp, 0, (size_t)NPART * NNODES * 4, stream);
    {
        int total = NNODES * 64;
        lin0_k<<<(total + 255) / 256, 256, 0, stream>>>(pos, l0w, l0b, x0h, total);
    }
    hist_k<<<(NEDGES + 255) / 256, 256, 0, stream>>>(dst, degp, rank, NEDGES);
    offs_k<<<NBLK, 256, 0, stream>>>(degp, poff, deg, NNODES);
    scan_part_k<<<NBLK, 256, 0, stream>>>(deg, bsum, NNODES);
    scan_mid_k<<<1, 512, 0, stream>>>(bsum, boff, NBLK, roff, NNODES);
    scan_final_k<<<NBLK, 256, 0, stream>>>(deg, boff, roff, NNODES);
    fill_k<<<(NEDGES + 255) / 256, 256, 0, stream>>>(src, dst, roff, poff, rank, csr, NEDGES);
    prep_k<<<(9 * 4 * 2 * 64 + 255) / 256, 256, 0, stream>>>(cw, l1w, Bpack);

    const int LBLOCKS = 2048;
    const f16* cur = x0h;
    for (int l = 0; l < NLAYERS; ++l) {
        float x0scale = (float)(0.1 * ldexp(1.0, -3 * l));   // 0.1 / 8^l
        f16* nxt = (l & 1) ? xB : xA;
        agg_k<<<2 * (NNODES / 16), 256, 0, stream>>>(cur, hbuf, x0h, roff, csr, x0scale);
        gemm_k<<<LBLOCKS, 256, 0, stream>>>(hbuf, nxt,
                                            Bpack + (size_t)l * 4 * 2 * 64 * 8,
                                            LBLOCKS, 1);
        cur = nxt;
    }
    // lin1 into the free buffer (cur == xB after 8 layers; xA is dead)
    f16* l1out = (cur == xA) ? xB : xA;
    gemm_k<<<LBLOCKS, 256, 0, stream>>>(cur, l1out,
                                        Bpack + (size_t)8 * 4 * 2 * 64 * 8, LBLOCKS, 0);
    segmax_k<<<NGRAPH * PPART, 256, 0, stream>>>(l1out, batch, pmax);
    poolcomb_k<<<(NGRAPH * 64 + 255) / 256, 256, 0, stream>>>(pmax, l1b, pooled);
    head_k<<<1, 256, 0, stream>>>(pooled, m1w, m1b, g1, b1, m2w, m2b, g2, b2, ow, ob, out);
}

// Round 21
// 546.877 us; speedup vs baseline: 1.6978x; 1.6978x over previous
//
#include <hip/hip_runtime.h>
#include <math.h>

#define NNODES 100000
#define NEDGES 1200000
#define HD 64
#define NLAYERS 8
#define NGRAPH 100
#define PPART 32          // pooling partitions per graph
#define NPART 8           // histogram partials (≈ XCD count)
#define C8 16777216.0f    // 8^8 = 2^24, exact in f32

typedef _Float16 f16;
typedef __attribute__((ext_vector_type(8))) _Float16 f16x8;
typedef __attribute__((ext_vector_type(4))) float f32x4;

// ---------- lin0: x0 = relu(pos @ lin0_w + lin0_b), fp16 (scale c_0 = 1) ----------
__global__ void lin0_k(const float* __restrict__ pos, const float* __restrict__ w,
                       const float* __restrict__ b, f16* __restrict__ x0h, int total) {
    int i = blockIdx.x * blockDim.x + threadIdx.x;
    if (i >= total) return;
    int n = i >> 6, h = i & 63;
    float p0 = pos[n * 3 + 0], p1 = pos[n * 3 + 1], p2 = pos[n * 3 + 2];
    float v = fmaf(p0, w[h], fmaf(p1, w[64 + h], fmaf(p2, w[128 + h], b[h])));
    x0h[i] = (f16)fmaxf(v, 0.0f);
}

// ---------- CSR build (XCD-local partial histograms) ----------
__global__ void hist_k(const int* __restrict__ dst, int* __restrict__ degp,
                       int* __restrict__ rank, int E) {
    int e = blockIdx.x * 256 + threadIdx.x;
    int p = blockIdx.x & (NPART - 1);
    if (e < E) rank[e] = atomicAdd(&degp[p * NNODES + dst[e]], 1);
}

__global__ void offs_k(const int* __restrict__ degp, int* __restrict__ poff,
                       int* __restrict__ deg, int n) {
    int d = blockIdx.x * blockDim.x + threadIdx.x;
    if (d >= n) return;
    int s = 0;
#pragma unroll
    for (int p = 0; p < NPART; ++p) {
        poff[p * n + d] = s;
        s += degp[p * n + d];
    }
    deg[d] = s;
}

__global__ void scan_part_k(const int* __restrict__ deg, int* __restrict__ bsum, int n) {
    __shared__ int s[256];
    int t = threadIdx.x;
    int i = blockIdx.x * 256 + t;
    s[t] = (i < n) ? deg[i] : 0;
    __syncthreads();
    for (int off = 128; off > 0; off >>= 1) {
        if (t < off) s[t] += s[t + off];
        __syncthreads();
    }
    if (t == 0) bsum[blockIdx.x] = s[0];
}

__global__ void scan_mid_k(const int* __restrict__ bsum, int* __restrict__ boff,
                           int nblk, int* __restrict__ roff, int n) {
    __shared__ int s[512];
    int t = threadIdx.x;
    int v = (t < nblk) ? bsum[t] : 0;
    s[t] = v;
    __syncthreads();
    for (int off = 1; off < 512; off <<= 1) {
        int u = (t >= off) ? s[t - off] : 0;
        __syncthreads();
        s[t] += u;
        __syncthreads();
    }
    if (t < nblk) boff[t] = s[t] - v;          // exclusive
    if (t == nblk - 1) roff[n] = s[t];         // == E
}

__global__ void scan_final_k(const int* __restrict__ deg, const int* __restrict__ boff,
                             int* __restrict__ roff, int n) {
    __shared__ int s[256];
    int t = threadIdx.x;
    int i = blockIdx.x * 256 + t;
    int v = (i < n) ? deg[i] : 0;
    s[t] = v;
    __syncthreads();
    for (int off = 1; off < 256; off <<= 1) {
        int u = (t >= off) ? s[t - off] : 0;
        __syncthreads();
        s[t] += u;
        __syncthreads();
    }
    if (i < n) roff[i] = boff[blockIdx.x] + s[t] - v;   // exclusive scan
}

__global__ void fill_k(const int* __restrict__ src, const int* __restrict__ dst,
                       const int* __restrict__ roff, const int* __restrict__ poff,
                       const int* __restrict__ rank, int* __restrict__ csr, int E) {
    int e = blockIdx.x * 256 + threadIdx.x;
    if (e < E) {
        int d = dst[e];
        int p = (e >> 8) & (NPART - 1);
        csr[roff[d] + poff[p * NNODES + d] + rank[e]] = src[e];
    }
}

// ---------- prep: pack 9 matrices into MFMA B-fragment order ----------
// mat 0..7: Mfold_l = (1/8)*((1-beta_l)*I + beta_l*W_l)   (layer GEMMs)
// mat 8:    l1w raw                                        (lin1 GEMM)
__global__ void prep_k(const float* __restrict__ cw, const float* __restrict__ l1w,
                       f16* __restrict__ Bpack) {
    int t = blockIdx.x * blockDim.x + threadIdx.x;
    if (t >= 9 * 4 * 2 * 64) return;
    int mat = t >> 9, rem = t & 511;
    int ct = rem >> 7, kk = (rem >> 6) & 1, lane = rem & 63;
    int g = lane >> 4, r = lane & 15;
    f16* outp = Bpack + (size_t)t * 8;
    if (mat < 8) {
        float beta = logf(0.5f / (float)(mat + 1) + 1.0f);
        const float* W = cw + (size_t)mat * 4096;
        for (int j = 0; j < 8; ++j) {
            int row = 32 * kk + 8 * g + j;
            int col = 16 * ct + r;
            float m = beta * W[row * 64 + col];
            if (row == col) m += 1.0f - beta;
            outp[j] = (f16)(0.125f * m);
        }
    } else {
        for (int j = 0; j < 8; ++j) {
            int row = 32 * kk + 8 * g + j;
            int col = 16 * ct + r;
            outp[j] = (f16)l1w[row * 64 + col];
        }
    }
}

// ---------- fused GCN2 layer: gather + residual + MFMA GEMM + relu ----------
// Best-measured structure (r16, 50.6us/layer ~= compulsory-L2-traffic floor:
// 67MB/layer of random 128B line fetches across 8 non-coherent L2 domains
// served at ~1.4 TB/s; verified by 6 structural variants r14-r20).
__global__ __launch_bounds__(256, 8) void layer_k(
    const f16* __restrict__ xin, f16* __restrict__ xout,
    const f16* __restrict__ x0, const f16* __restrict__ Bp,
    const int* __restrict__ roff, const int* __restrict__ csr,
    float x0scale, int nblocks) {
    __shared__ __align__(16) f16 Htile[16][72];   // 72 = 64 + 8 pad
    const int tid   = threadIdx.x;
    const int lane  = tid & 63;
    const int wslot = tid >> 6;
    const f16x8 b0 = *(const f16x8*)(Bp + (size_t)((wslot * 2 + 0) * 64 + lane) * 8);
    const f16x8 b1 = *(const f16x8*)(Bp + (size_t)((wslot * 2 + 1) * 64 + lane) * 8);
    for (int tile = blockIdx.x; tile < NNODES / 16; tile += nblocks) {
        const int nbase = tile << 4;
#pragma unroll 1
        for (int i = 0; i < 4; ++i) {
            const int n = nbase + (wslot << 2) + i;
            const int beg = roff[n], end = roff[n + 1];
            float x0v = (float)x0[(n << 6) + lane];
            float s0 = 0.0f, s1 = 0.0f, s2 = 0.0f, s3 = 0.0f;
            int e = beg;
            for (; e + 8 <= end; e += 8) {
                int i0 = csr[e + 0], i1 = csr[e + 1], i2 = csr[e + 2], i3 = csr[e + 3];
                int i4 = csr[e + 4], i5 = csr[e + 5], i6 = csr[e + 6], i7 = csr[e + 7];
                f16 v0 = xin[(i0 << 6) + lane];
                f16 v1 = xin[(i1 << 6) + lane];
                f16 v2 = xin[(i2 << 6) + lane];
                f16 v3 = xin[(i3 << 6) + lane];
                f16 v4 = xin[(i4 << 6) + lane];
                f16 v5 = xin[(i5 << 6) + lane];
                f16 v6 = xin[(i6 << 6) + lane];
                f16 v7 = xin[(i7 << 6) + lane];
                s0 += (float)v0; s1 += (float)v1; s2 += (float)v2; s3 += (float)v3;
                s0 += (float)v4; s1 += (float)v5; s2 += (float)v6; s3 += (float)v7;
            }
            for (; e + 4 <= end; e += 4) {
                int i0 = csr[e + 0], i1 = csr[e + 1], i2 = csr[e + 2], i3 = csr[e + 3];
                s0 += (float)xin[(i0 << 6) + lane];
                s1 += (float)xin[(i1 << 6) + lane];
                s2 += (float)xin[(i2 << 6) + lane];
                s3 += (float)xin[(i3 << 6) + lane];
            }
            for (; e < end; ++e) s0 += (float)xin[(csr[e] << 6) + lane];
            float h = fmaf(0.9f, (s0 + s1) + (s2 + s3), x0scale * x0v);
            Htile[(wslot << 2) + i][lane] = (f16)h;
        }
        __syncthreads();
        const int ar = lane & 15, ag = lane >> 4;
        f16x8 a0 = *(const f16x8*)&Htile[ar][(ag << 3) + 0];
        f16x8 a1 = *(const f16x8*)&Htile[ar][(ag << 3) + 32];
        f32x4 acc = {0.0f, 0.0f, 0.0f, 0.0f};
        acc = __builtin_amdgcn_mfma_f32_16x16x32_f16(a0, b0, acc, 0, 0, 0);
        acc = __builtin_amdgcn_mfma_f32_16x16x32_f16(a1, b1, acc, 0, 0, 0);
        const int col = (wslot << 4) + ar;
        const int rbase = nbase + (ag << 2);
#pragma unroll
        for (int j = 0; j < 4; ++j) {
            xout[((rbase + j) << 6) + col] = (f16)fmaxf(acc[j], 0.0f);
        }
        __syncthreads();
    }
}

// ---------- lin1 as pure MFMA GEMM ----------
__global__ __launch_bounds__(256, 8) void lin1_k(
    const f16* __restrict__ xin, f16* __restrict__ yout,
    const f16* __restrict__ Bp, int nblocks) {
    const int lane  = threadIdx.x & 63;
    const int wslot = threadIdx.x >> 6;
    const f16x8 b0 = *(const f16x8*)(Bp + (size_t)((wslot * 2 + 0) * 64 + lane) * 8);
    const f16x8 b1 = *(const f16x8*)(Bp + (size_t)((wslot * 2 + 1) * 64 + lane) * 8);
    const int ar = lane & 15, ag = lane >> 4;
    for (int tile = blockIdx.x; tile < NNODES / 16; tile += nblocks) {
        const int nbase = tile << 4;
        f16x8 a0 = *(const f16x8*)(xin + ((size_t)(nbase + ar) << 6) + (ag << 3));
        f16x8 a1 = *(const f16x8*)(xin + ((size_t)(nbase + ar) << 6) + (ag << 3) + 32);
        f32x4 acc = {0.0f, 0.0f, 0.0f, 0.0f};
        acc = __builtin_amdgcn_mfma_f32_16x16x32_f16(a0, b0, acc, 0, 0, 0);
        acc = __builtin_amdgcn_mfma_f32_16x16x32_f16(a1, b1, acc, 0, 0, 0);
        const int col = (wslot << 4) + ar;
        const int rbase = nbase + (ag << 2);
#pragma unroll
        for (int j = 0; j < 4; ++j) {
            yout[((rbase + j) << 6) + col] = (f16)acc[j];   // stored units
        }
    }
}

// ---------- segment max over lin1 output (pure fp16 row-max) ----------
__device__ __forceinline__ int lbound(const int* __restrict__ a, int n, int v) {
    int lo = 0, hi = n;
    while (lo < hi) { int mid = (lo + hi) >> 1; if (a[mid] < v) lo = mid + 1; else hi = mid; }
    return lo;
}

__global__ __launch_bounds__(256, 8) void segmax_k(
    const f16* __restrict__ y, const int* __restrict__ batch,
    float* __restrict__ pmax) {
    __shared__ float wm[4][64];
    const int tid   = threadIdx.x;
    const int lane  = tid & 63;
    const int wslot = tid >> 6;
    const int g = blockIdx.x / PPART, part = blockIdx.x % PPART;
    const int lo = lbound(batch, NNODES, g);
    const int hi = lbound(batch, NNODES, g + 1);
    const int cnt = hi - lo;
    const int qlo = lo + (cnt * part) / PPART;
    const int qhi = lo + (cnt * (part + 1)) / PPART;
    float vmax = -INFINITY;
    for (int n = qlo + wslot; n < qhi; n += 4)
        vmax = fmaxf(vmax, (float)y[(n << 6) + lane]);
    wm[wslot][lane] = vmax;
    __syncthreads();
    if (tid < 64) {
        float m = fmaxf(fmaxf(wm[0][tid], wm[1][tid]), fmaxf(wm[2][tid], wm[3][tid]));
        pmax[blockIdx.x * 64 + tid] = m;
    }
}

// combine partitions + undo 8^8 scale + add bias (max commutes with affine)
__global__ void poolcomb_k(const float* __restrict__ pmax,
                           const float* __restrict__ bvec,
                           float* __restrict__ pooled) {
    int i = blockIdx.x * blockDim.x + threadIdx.x;
    if (i >= NGRAPH * 64) return;
    int g = i >> 6, lane = i & 63;
    float m = -INFINITY;
    for (int p = 0; p < PPART; ++p)
        m = fmaxf(m, pmax[(PPART * g + p) * 64 + lane]);
    pooled[i] = fmaf(C8, m, bvec[lane]);   // -inf stays -inf; head guards
}

// ---------- head: MLP + BN + out + log_softmax, single block ----------
__global__ __launch_bounds__(256) void head_k(
    const float* __restrict__ pooled,
    const float* __restrict__ m1w, const float* __restrict__ m1b,
    const float* __restrict__ g1, const float* __restrict__ be1,
    const float* __restrict__ m2w, const float* __restrict__ m2b,
    const float* __restrict__ g2, const float* __restrict__ be2,
    const float* __restrict__ ow, const float* __restrict__ ob,
    float* __restrict__ out) {
    __shared__ float A[NGRAPH * 64];
    __shared__ float B[NGRAPH * 64];
    __shared__ float mu[64], rs[64];
    __shared__ float LG[NGRAPH * 10];
    int t = threadIdx.x;
    for (int i = t; i < NGRAPH * 64; i += 256) {
        float f = pooled[i];
        if (!isfinite(f)) f = 0.0f;   // empty-segment guard
        A[i] = f;
    }
    __syncthreads();
    // ---- mlp1 ----
    for (int i = t; i < NGRAPH * 64; i += 256) {
        int g = i >> 6, j = i & 63;
        float acc = m1b[j];
        for (int k = 0; k < 64; ++k) acc = fmaf(A[(g << 6) + k], m1w[k * 64 + j], acc);
        B[i] = acc;
    }
    __syncthreads();
    if (t < 64) {
        float sm = 0.0f, sq = 0.0f;
        for (int g = 0; g < NGRAPH; ++g) { float z = B[g * 64 + t]; sm += z; sq += z * z; }
        float m = sm * (1.0f / NGRAPH);
        float var = sq * (1.0f / NGRAPH) - m * m;
        mu[t] = m; rs[t] = rsqrtf(var + 1e-5f);
    }
    __syncthreads();
    for (int i = t; i < NGRAPH * 64; i += 256) {
        int j = i & 63;
        float z = fmaf((B[i] - mu[j]) * rs[j], g1[j], be1[j]);
        A[i] = fmaxf(z, 0.0f);
    }
    __syncthreads();
    // ---- mlp2 ----
    for (int i = t; i < NGRAPH * 64; i += 256) {
        int g = i >> 6, j = i & 63;
        float acc = m2b[j];
        for (int k = 0; k < 64; ++k) acc = fmaf(A[(g << 6) + k], m2w[k * 64 + j], acc);
        B[i] = acc;
    }
    __syncthreads();
    if (t < 64) {
        float sm = 0.0f, sq = 0.0f;
        for (int g = 0; g < NGRAPH; ++g) { float z = B[g * 64 + t]; sm += z; sq += z * z; }
        float m = sm * (1.0f / NGRAPH);
        float var = sq * (1.0f / NGRAPH) - m * m;
        mu[t] = m; rs[t] = rsqrtf(var + 1e-5f);
    }
    __syncthreads();
    for (int i = t; i < NGRAPH * 64; i += 256) {
        int j = i & 63;
        float z = fmaf((B[i] - mu[j]) * rs[j], g2[j], be2[j]);
        A[i] = fmaxf(z, 0.0f);
    }
    __syncthreads();
    // ---- out + log_softmax ----
    for (int i = t; i < NGRAPH * 10; i += 256) {
        int g = i / 10, j = i - g * 10;
        float acc = ob[j];
        for (int k = 0; k < 64; ++k) acc = fmaf(A[(g << 6) + k], ow[k * 10 + j], acc);
        LG[i] = acc;
    }
    __syncthreads();
    if (t < NGRAPH) {
        float m = -1e30f;
        for (int j = 0; j < 10; ++j) m = fmaxf(m, LG[t * 10 + j]);
        float s = 0.0f;
        for (int j = 0; j < 10; ++j) s += expf(LG[t * 10 + j] - m);
        float lse = m + logf(s);
        for (int j = 0; j < 10; ++j) out[t * 10 + j] = LG[t * 10 + j] - lse;
    }
}

extern "C" void kernel_launch(void* const* d_in, const int* in_sizes, int n_in,
                              void* d_out, int out_size, void* d_ws, size_t ws_size,
                              hipStream_t stream) {
    const float* pos   = (const float*)d_in[0];
    const int*   eidx  = (const int*)d_in[1];
    const int*   batch = (const int*)d_in[2];
    const float* l0w   = (const float*)d_in[3];
    const float* l0b   = (const float*)d_in[4];
    const float* cw    = (const float*)d_in[5];
    const float* l1w   = (const float*)d_in[6];
    const float* l1b   = (const float*)d_in[7];
    const float* m1w   = (const float*)d_in[8];
    const float* m1b   = (const float*)d_in[9];
    const float* g1    = (const float*)d_in[10];
    const float* b1    = (const float*)d_in[11];
    const float* m2w   = (const float*)d_in[12];
    const float* m2b   = (const float*)d_in[13];
    const float* g2    = (const float*)d_in[14];
    const float* b2    = (const float*)d_in[15];
    const float* ow    = (const float*)d_in[16];
    const float* ob    = (const float*)d_in[17];
    float* out = (float*)d_out;
    const int* src = eidx;
    const int* dst = eidx + NEDGES;

    size_t off = 0;
    auto alloc = [&](size_t bytes) -> void* {
        void* p = (char*)d_ws + off;
        off += (bytes + 255) & ~(size_t)255;
        return p;
    };
    f16*   x0h    = (f16*)alloc((size_t)NNODES * 64 * 2);
    f16*   xA     = (f16*)alloc((size_t)NNODES * 64 * 2);
    f16*   xB     = (f16*)alloc((size_t)NNODES * 64 * 2);
    int*   deg    = (int*)alloc((size_t)NNODES * 4);
    int*   degp   = (int*)alloc((size_t)NPART * NNODES * 4);   // 3.2MB
    int*   poff   = (int*)alloc((size_t)NPART * NNODES * 4);   // 3.2MB
    int*   roff   = (int*)alloc((size_t)(NNODES + 1) * 4);
    const int NBLK = (NNODES + 255) / 256;                     // 391
    int*   bsum   = (int*)alloc((size_t)NBLK * 4);
    int*   boff   = (int*)alloc((size_t)NBLK * 4);
    int*   csr    = (int*)alloc((size_t)NEDGES * 4);
    float* pooled = (float*)alloc((size_t)NGRAPH * 64 * 4);
    float* pmax   = (float*)alloc((size_t)NGRAPH * PPART * 64 * 4);
    f16*   Bpack  = (f16*)alloc((size_t)9 * 4 * 2 * 64 * 8 * 2);   // 72KB
    int*   rank   = (int*)xB;   // xB dead until layer 1 writes it

    hipMemsetAsync(degp, 0, (size_t)NPART * NNODES * 4, stream);
    {
        int total = NNODES * 64;
        lin0_k<<<(total + 255) / 256, 256, 0, stream>>>(pos, l0w, l0b, x0h, total);
    }
    hist_k<<<(NEDGES + 255) / 256, 256, 0, stream>>>(dst, degp, rank, NEDGES);
    offs_k<<<NBLK, 256, 0, stream>>>(degp, poff, deg, NNODES);
    scan_part_k<<<NBLK, 256, 0, stream>>>(deg, bsum, NNODES);
    scan_mid_k<<<1, 512, 0, stream>>>(bsum, boff, NBLK, roff, NNODES);
    scan_final_k<<<NBLK, 256, 0, stream>>>(deg, boff, roff, NNODES);
    fill_k<<<(NEDGES + 255) / 256, 256, 0, stream>>>(src, dst, roff, poff, rank, csr, NEDGES);
    prep_k<<<(9 * 4 * 2 * 64 + 255) / 256, 256, 0, stream>>>(cw, l1w, Bpack);

    const int LBLOCKS = 2048;
    const f16* cur = x0h;
    for (int l = 0; l < NLAYERS; ++l) {
        float x0scale = (float)(0.1 * ldexp(1.0, -3 * l));   // 0.1 / 8^l
        f16* nxt = (l & 1) ? xB : xA;
        layer_k<<<LBLOCKS, 256, 0, stream>>>(cur, nxt, x0h,
                                             Bpack + (size_t)l * 4 * 2 * 64 * 8,
                                             roff, csr, x0scale, LBLOCKS);
        cur = nxt;
    }
    // lin1 into the free buffer (cur == xB after 8 layers; xA is dead)
    f16* l1out = (cur == xA) ? xB : xA;
    lin1_k<<<LBLOCKS, 256, 0, stream>>>(cur, l1out,
                                        Bpack + (size_t)8 * 4 * 2 * 64 * 8, LBLOCKS);
    segmax_k<<<NGRAPH * PPART, 256, 0, stream>>>(l1out, batch, pmax);
    poolcomb_k<<<(NGRAPH * 64 + 255) / 256, 256, 0, stream>>>(pmax, l1b, pooled);
    head_k<<<1, 256, 0, stream>>>(pooled, m1w, m1b, g1, b1, m2w, m2b, g2, b2, ow, ob, out);
}